// Round 1
// baseline (10895.490 us; speedup 1.0000x reference)
//
#include <hip/hip_runtime.h>

#define N_NODES 200000
#define N_EDGES 6400000
#define D_IN 128
#define D_HID 16
#define D_OUT 172

// ---------------------------------------------------------------------------
// K1: zero the integer degree counters
__global__ __launch_bounds__(256) void k_init_deg(int* __restrict__ deg) {
    int i = blockIdx.x * 256 + threadIdx.x;
    if (i < N_NODES) deg[i] = 0;
}

// K2: in-degree histogram over dst (self-loop added later as +1)
__global__ __launch_bounds__(256) void k_deg(const int* __restrict__ dst,
                                             int* __restrict__ deg) {
    int e = blockIdx.x * 256 + threadIdx.x;
    if (e < N_EDGES) atomicAdd(&deg[dst[e]], 1);
}

// K3: dinv = rsqrt(deg + 1), in place (int -> float)
__global__ __launch_bounds__(256) void k_dinv(float* __restrict__ dinv) {
    int i = blockIdx.x * 256 + threadIdx.x;
    if (i < N_NODES) {
        int c = ((const int*)dinv)[i];
        dinv[i] = rsqrtf((float)(c + 1));
    }
}

// ---------------------------------------------------------------------------
// K4: lin = x @ W1  [N,128]x[128,16] -> [N,16]; also write agg1 self-loop init
//     agg_init[n] = lin[n] * dinv[n]^2
// Block = 256 threads = 64 nodes x 4 k-chunks. W1 staged in LDS.
__global__ __launch_bounds__(256) void k_lin1(const float* __restrict__ x,
                                              const float* __restrict__ W1,
                                              const float* __restrict__ dinv,
                                              float* __restrict__ lin,
                                              float* __restrict__ agg) {
    __shared__ float sW[D_IN * D_HID];  // 8 KB, [k][j]
    for (int t = threadIdx.x; t < D_IN * D_HID; t += 256) sW[t] = W1[t];
    __syncthreads();

    int g  = threadIdx.x & 3;    // k-chunk group: k in [g*32, g*32+32)
    int nl = threadIdx.x >> 2;   // local node 0..63
    int n  = blockIdx.x * 64 + nl;   // grid sized exactly: 3125*64 = 200000

    float acc[16];
#pragma unroll
    for (int j = 0; j < 16; ++j) acc[j] = 0.f;

    const float4* xr = (const float4*)(x + (size_t)n * D_IN + g * 32);
#pragma unroll
    for (int i = 0; i < 8; ++i) {
        float4 xv = xr[i];
        int k = g * 32 + i * 4;
#pragma unroll
        for (int j = 0; j < 16; ++j) {
            acc[j] += xv.x * sW[(k + 0) * 16 + j] + xv.y * sW[(k + 1) * 16 + j]
                    + xv.z * sW[(k + 2) * 16 + j] + xv.w * sW[(k + 3) * 16 + j];
        }
    }
    // reduce the 4 k-chunks (4 consecutive lanes, always within one wave)
#pragma unroll
    for (int j = 0; j < 16; ++j) {
        acc[j] += __shfl_xor(acc[j], 1);
        acc[j] += __shfl_xor(acc[j], 2);
    }
    float di = dinv[n];
    float w  = di * di;
    float4 o;
    o.x = acc[g * 4 + 0]; o.y = acc[g * 4 + 1];
    o.z = acc[g * 4 + 2]; o.w = acc[g * 4 + 3];
    *(float4*)(lin + (size_t)n * 16 + g * 4) = o;
    float4 oa; oa.x = o.x * w; oa.y = o.y * w; oa.z = o.z * w; oa.w = o.w * w;
    *(float4*)(agg + (size_t)n * 16 + g * 4) = oa;
}

// ---------------------------------------------------------------------------
// K5/K7: edge scatter-add in 16-dim: agg[dst] += fin[src] * dinv[src]*dinv[dst]
__global__ __launch_bounds__(256) void k_edge(const int* __restrict__ src,
                                              const int* __restrict__ dst,
                                              const float* __restrict__ dinv,
                                              const float* __restrict__ fin,
                                              float* __restrict__ agg) {
    int e = blockIdx.x * 256 + threadIdx.x;
    if (e >= N_EDGES) return;
    int s = src[e], d = dst[e];
    float w = dinv[s] * dinv[d];
    const float4* L = (const float4*)(fin + (size_t)s * 16);
    float4 a = L[0], b = L[1], c = L[2], dd = L[3];
    float* o = agg + (size_t)d * 16;
    unsafeAtomicAdd(o + 0,  a.x * w);  unsafeAtomicAdd(o + 1,  a.y * w);
    unsafeAtomicAdd(o + 2,  a.z * w);  unsafeAtomicAdd(o + 3,  a.w * w);
    unsafeAtomicAdd(o + 4,  b.x * w);  unsafeAtomicAdd(o + 5,  b.y * w);
    unsafeAtomicAdd(o + 6,  b.z * w);  unsafeAtomicAdd(o + 7,  b.w * w);
    unsafeAtomicAdd(o + 8,  c.x * w);  unsafeAtomicAdd(o + 9,  c.y * w);
    unsafeAtomicAdd(o + 10, c.z * w);  unsafeAtomicAdd(o + 11, c.w * w);
    unsafeAtomicAdd(o + 12, dd.x * w); unsafeAtomicAdd(o + 13, dd.y * w);
    unsafeAtomicAdd(o + 14, dd.z * w); unsafeAtomicAdd(o + 15, dd.w * w);
}

// ---------------------------------------------------------------------------
// K6: h = relu(agg1 + b1) in place; agg2_init = h * dinv^2
__global__ __launch_bounds__(256) void k_relu_init(float4* __restrict__ h,
                                                   const float* __restrict__ b1,
                                                   const float* __restrict__ dinv,
                                                   float4* __restrict__ agg2) {
    int i = blockIdx.x * 256 + threadIdx.x;   // over N_NODES*4 float4s (exact)
    int n = i >> 2, q = i & 3;
    float4 bv = ((const float4*)b1)[q];
    float4 v = h[i];
    v.x = fmaxf(v.x + bv.x, 0.f);
    v.y = fmaxf(v.y + bv.y, 0.f);
    v.z = fmaxf(v.z + bv.z, 0.f);
    v.w = fmaxf(v.w + bv.w, 0.f);
    h[i] = v;
    float di = dinv[n];
    float w  = di * di;
    float4 o; o.x = v.x * w; o.y = v.y * w; o.z = v.z * w; o.w = v.w * w;
    agg2[i] = o;
}

// ---------------------------------------------------------------------------
// K8: logits = agg2 @ W2 + b2; out = log_softmax(logits). One wave per node.
__global__ __launch_bounds__(256) void k_out(const float* __restrict__ agg2,
                                             const float* __restrict__ W2,
                                             const float* __restrict__ b2,
                                             float* __restrict__ out) {
    __shared__ float sW[D_HID * D_OUT];  // [k][c], 11 KB
    __shared__ float sb[D_OUT];
    for (int t = threadIdx.x; t < D_HID * D_OUT; t += 256) sW[t] = W2[t];
    for (int t = threadIdx.x; t < D_OUT; t += 256) sb[t] = b2[t];
    __syncthreads();

    int wid = threadIdx.x >> 6, lane = threadIdx.x & 63;
    int n = blockIdx.x * 4 + wid;    // grid exact: 50000*4 = 200000
    const float4* ar = (const float4*)(agg2 + (size_t)n * 16);
    float4 a0 = ar[0], a1 = ar[1], a2 = ar[2], a3 = ar[3];
    float a[16] = {a0.x, a0.y, a0.z, a0.w, a1.x, a1.y, a1.z, a1.w,
                   a2.x, a2.y, a2.z, a2.w, a3.x, a3.y, a3.z, a3.w};

    bool has2 = (lane < D_OUT - 128);            // 44 lanes carry a 3rd class
    int  c2   = has2 ? lane + 128 : 0;           // clamped to stay in-bounds
    float l0 = sb[lane], l1 = sb[lane + 64];
    float l2 = has2 ? sb[c2] : -INFINITY;
#pragma unroll
    for (int k = 0; k < 16; ++k) {
        float av = a[k];
        l0 += av * sW[k * D_OUT + lane];
        l1 += av * sW[k * D_OUT + lane + 64];
        l2 += av * sW[k * D_OUT + c2];           // -inf + finite = -inf for !has2
    }
    float m = fmaxf(fmaxf(l0, l1), l2);
#pragma unroll
    for (int o = 1; o < 64; o <<= 1) m = fmaxf(m, __shfl_xor(m, o));
    float e0 = __expf(l0 - m), e1 = __expf(l1 - m);
    float e2 = has2 ? __expf(l2 - m) : 0.f;
    float s = e0 + e1 + e2;
#pragma unroll
    for (int o = 1; o < 64; o <<= 1) s += __shfl_xor(s, o);
    float ls = m + __logf(s);
    float* op = out + (size_t)n * D_OUT;
    op[lane]      = l0 - ls;
    op[lane + 64] = l1 - ls;
    if (has2) op[lane + 128] = l2 - ls;
}

// ---------------------------------------------------------------------------
extern "C" void kernel_launch(void* const* d_in, const int* in_sizes, int n_in,
                              void* d_out, int out_size, void* d_ws, size_t ws_size,
                              hipStream_t stream) {
    const float* x    = (const float*)d_in[0];
    const int*   edges = (const int*)d_in[1];       // [2, N_EDGES] row-major
    const float* W1   = (const float*)d_in[2];
    const float* b1   = (const float*)d_in[3];
    const float* W2   = (const float*)d_in[4];
    const float* b2   = (const float*)d_in[5];
    float*       out  = (float*)d_out;

    const int* src = edges;
    const int* dst = edges + N_EDGES;

    // workspace layout (floats): dinv[200000] | bufA[3.2M] | bufB[3.2M]
    float* ws   = (float*)d_ws;
    float* dinv = ws;                         // also used as int* for histogram
    float* bufA = ws + 200704;                // lin1, later agg2 (4KB-aligned)
    float* bufB = bufA + (size_t)N_NODES * D_HID;  // agg1, later h

    const int B = 256;
    k_init_deg<<<(N_NODES + B - 1) / B, B, 0, stream>>>((int*)dinv);
    k_deg<<<N_EDGES / B, B, 0, stream>>>(dst, (int*)dinv);
    k_dinv<<<(N_NODES + B - 1) / B, B, 0, stream>>>(dinv);

    // layer 1: lin1 = x@W1 (+ self-loop init of agg1), then edge scatter
    k_lin1<<<N_NODES / 64, B, 0, stream>>>(x, W1, dinv, bufA, bufB);
    k_edge<<<N_EDGES / B, B, 0, stream>>>(src, dst, dinv, bufA, bufB);

    // relu+bias -> h (in place on bufB); agg2 self-loop init into bufA
    k_relu_init<<<(N_NODES * 4) / B, B, 0, stream>>>((float4*)bufB, b1, dinv,
                                                     (float4*)bufA);
    // layer 2 aggregation in 16-dim (reassociated: (A@h)@W2)
    k_edge<<<N_EDGES / B, B, 0, stream>>>(src, dst, dinv, bufB, bufA);

    // 16->172 GEMM + bias + log_softmax
    k_out<<<N_NODES / 4, B, 0, stream>>>(bufA, W2, b2, out);
}

// Round 2
// 896.650 us; speedup vs baseline: 12.1513x; 12.1513x over previous
//
#include <hip/hip_runtime.h>

#define N_NODES 200000
#define N_PAD   200704   // 784 * 256
#define N_EDGES 6400000
#define D_IN    128
#define D_HID   16
#define D_OUT   172

// workspace layout in 4-byte units (total 13,403,136 * 4B = 53.6 MB)
#define O_DEG   0               // int[200704]  degree counts (zero-padded for scan)
#define O_ROW   200704          // int[200704]  CSR rowptr (exclusive scan of deg)
#define O_BSUM  401408          // int[1024]    per-block sums for scan
#define O_DINV  402432          // float[200704] rsqrt(deg+1)
#define O_POS   603136          // int[6.4M]    per-edge slot (dead after k_fill)
#define O_BUFA  603136          // float[3.2M]  lin1 / agg2   (aliases POS)
#define O_BUFB  3803136         // float[3.2M]  agg1 / h      (aliases POS)
#define O_COL   7003136         // int[6.4M]    CSR column (src) indices

// ---------------------------------------------------------------------------
__global__ __launch_bounds__(256) void k_init_deg(int* __restrict__ deg) {
    int i = blockIdx.x * 256 + threadIdx.x;   // grid covers N_PAD exactly
    deg[i] = 0;
}

// histogram over dst; returned old count = this edge's slot within its row
__global__ __launch_bounds__(256) void k_hist(const int* __restrict__ dst,
                                              int* __restrict__ deg,
                                              int* __restrict__ pos) {
    int e = blockIdx.x * 256 + threadIdx.x;
    pos[e] = atomicAdd(&deg[dst[e]], 1);
}

// per-block (256-wide) sums of deg -> bsum
__global__ __launch_bounds__(256) void k_bsum(const int* __restrict__ deg,
                                              int* __restrict__ bsum) {
    __shared__ int s[256];
    int i = blockIdx.x * 256 + threadIdx.x;
    s[threadIdx.x] = deg[i];
    __syncthreads();
    for (int o = 128; o > 0; o >>= 1) {
        if (threadIdx.x < o) s[threadIdx.x] += s[threadIdx.x + o];
        __syncthreads();
    }
    if (threadIdx.x == 0) bsum[blockIdx.x] = s[0];
}

// exclusive scan of the 784 block sums (single block, serial in LDS)
__global__ __launch_bounds__(256) void k_scan_bsum(int* __restrict__ bsum) {
    __shared__ int s[784];
    for (int t = threadIdx.x; t < 784; t += 256) s[t] = bsum[t];
    __syncthreads();
    if (threadIdx.x == 0) {
        int run = 0;
        for (int i = 0; i < 784; ++i) { int v = s[i]; s[i] = run; run += v; }
    }
    __syncthreads();
    for (int t = threadIdx.x; t < 784; t += 256) bsum[t] = s[t];
}

// final exclusive scan: rowptr[i] = bsum[blk] + exclusive-scan-within-block
__global__ __launch_bounds__(256) void k_scan_final(const int* __restrict__ deg,
                                                    const int* __restrict__ bsum,
                                                    int* __restrict__ rowptr) {
    __shared__ int wsum[4];
    int i = blockIdx.x * 256 + threadIdx.x;
    int lane = threadIdx.x & 63, wid = threadIdx.x >> 6;
    int v = deg[i];
    int incl = v;
#pragma unroll
    for (int o = 1; o < 64; o <<= 1) {
        int t = __shfl_up(incl, o);
        if (lane >= o) incl += t;
    }
    if (lane == 63) wsum[wid] = incl;
    __syncthreads();
    int add = 0;
    for (int w = 0; w < wid; ++w) add += wsum[w];
    rowptr[i] = bsum[blockIdx.x] + add + incl - v;
}

// dinv = rsqrt(deg+1)  (self-loop adds 1)
__global__ __launch_bounds__(256) void k_dinv(const int* __restrict__ deg,
                                              float* __restrict__ dinv) {
    int i = blockIdx.x * 256 + threadIdx.x;
    if (i < N_NODES) dinv[i] = rsqrtf((float)(deg[i] + 1));
}

// scatter edge src ids into CSR slots (no atomics: slot = rowptr[dst]+pos)
__global__ __launch_bounds__(256) void k_fill(const int* __restrict__ src,
                                              const int* __restrict__ dst,
                                              const int* __restrict__ pos,
                                              const int* __restrict__ rowptr,
                                              int* __restrict__ col) {
    int e = blockIdx.x * 256 + threadIdx.x;
    col[rowptr[dst[e]] + pos[e]] = src[e];
}

// ---------------------------------------------------------------------------
// lin = x @ W1  [N,128]x[128,16] -> [N,16]. 256 thr = 64 nodes x 4 k-chunks.
__global__ __launch_bounds__(256) void k_lin1(const float* __restrict__ x,
                                              const float* __restrict__ W1,
                                              float* __restrict__ lin) {
    __shared__ float sW[D_IN * D_HID];  // 8 KB, [k][j]
    for (int t = threadIdx.x; t < D_IN * D_HID; t += 256) sW[t] = W1[t];
    __syncthreads();

    int g  = threadIdx.x & 3;
    int nl = threadIdx.x >> 2;
    int n  = blockIdx.x * 64 + nl;   // grid exact: 3125*64

    float acc[16];
#pragma unroll
    for (int j = 0; j < 16; ++j) acc[j] = 0.f;

    const float4* xr = (const float4*)(x + (size_t)n * D_IN + g * 32);
#pragma unroll
    for (int i = 0; i < 8; ++i) {
        float4 xv = xr[i];
        int k = g * 32 + i * 4;
#pragma unroll
        for (int j = 0; j < 16; ++j) {
            acc[j] += xv.x * sW[(k + 0) * 16 + j] + xv.y * sW[(k + 1) * 16 + j]
                    + xv.z * sW[(k + 2) * 16 + j] + xv.w * sW[(k + 3) * 16 + j];
        }
    }
#pragma unroll
    for (int j = 0; j < 16; ++j) {
        acc[j] += __shfl_xor(acc[j], 1);
        acc[j] += __shfl_xor(acc[j], 2);
    }
    float4 o;
    o.x = acc[g * 4 + 0]; o.y = acc[g * 4 + 1];
    o.z = acc[g * 4 + 2]; o.w = acc[g * 4 + 3];
    *(float4*)(lin + (size_t)n * 16 + g * 4) = o;
}

// ---------------------------------------------------------------------------
// pull aggregation: agg[n] = fin[n]*dinv[n]^2 + sum_{s in row(n)} fin[s]*dinv[s]*dinv[n]
// 16 lanes per node, one float per lane.
__global__ __launch_bounds__(256) void k_gather(const int* __restrict__ rowptr,
                                                const int* __restrict__ col,
                                                const float* __restrict__ dinv,
                                                const float* __restrict__ fin,
                                                float* __restrict__ agg) {
    int n    = blockIdx.x * 16 + (threadIdx.x >> 4);  // grid exact: 12500*16
    int lane = threadIdx.x & 15;
    float dd  = dinv[n];
    float acc = fin[(size_t)n * 16 + lane] * dd * dd;  // self loop
    int beg = rowptr[n], end = rowptr[n + 1];
    int s_next = (beg < end) ? col[beg] : 0;
    for (int i = beg; i < end; ) {
        int s = s_next;
        ++i;
        if (i < end) s_next = col[i];     // 1-ahead prefetch of col
        acc += fin[(size_t)s * 16 + lane] * (dinv[s] * dd);
    }
    agg[(size_t)n * 16 + lane] = acc;
}

// h = relu(agg1 + b1) in place
__global__ __launch_bounds__(256) void k_relu(float4* __restrict__ h,
                                              const float* __restrict__ b1) {
    int i = blockIdx.x * 256 + threadIdx.x;   // over N_NODES*4 float4s (exact)
    int q = i & 3;
    float4 bv = ((const float4*)b1)[q];
    float4 v = h[i];
    v.x = fmaxf(v.x + bv.x, 0.f);
    v.y = fmaxf(v.y + bv.y, 0.f);
    v.z = fmaxf(v.z + bv.z, 0.f);
    v.w = fmaxf(v.w + bv.w, 0.f);
    h[i] = v;
}

// ---------------------------------------------------------------------------
// logits = agg2 @ W2 + b2; out = log_softmax(logits). One wave per node.
__global__ __launch_bounds__(256) void k_out(const float* __restrict__ agg2,
                                             const float* __restrict__ W2,
                                             const float* __restrict__ b2,
                                             float* __restrict__ out) {
    __shared__ float sW[D_HID * D_OUT];
    __shared__ float sb[D_OUT];
    for (int t = threadIdx.x; t < D_HID * D_OUT; t += 256) sW[t] = W2[t];
    for (int t = threadIdx.x; t < D_OUT; t += 256) sb[t] = b2[t];
    __syncthreads();

    int wid = threadIdx.x >> 6, lane = threadIdx.x & 63;
    int n = blockIdx.x * 4 + wid;    // grid exact: 50000*4
    const float4* ar = (const float4*)(agg2 + (size_t)n * 16);
    float4 a0 = ar[0], a1 = ar[1], a2 = ar[2], a3 = ar[3];
    float a[16] = {a0.x, a0.y, a0.z, a0.w, a1.x, a1.y, a1.z, a1.w,
                   a2.x, a2.y, a2.z, a2.w, a3.x, a3.y, a3.z, a3.w};

    bool has2 = (lane < D_OUT - 128);
    int  c2   = has2 ? lane + 128 : 0;
    float l0 = sb[lane], l1 = sb[lane + 64];
    float l2 = has2 ? sb[c2] : -INFINITY;
#pragma unroll
    for (int k = 0; k < 16; ++k) {
        float av = a[k];
        l0 += av * sW[k * D_OUT + lane];
        l1 += av * sW[k * D_OUT + lane + 64];
        l2 += av * sW[k * D_OUT + c2];
    }
    float m = fmaxf(fmaxf(l0, l1), l2);
#pragma unroll
    for (int o = 1; o < 64; o <<= 1) m = fmaxf(m, __shfl_xor(m, o));
    float e0 = __expf(l0 - m), e1 = __expf(l1 - m);
    float e2 = has2 ? __expf(l2 - m) : 0.f;
    float s = e0 + e1 + e2;
#pragma unroll
    for (int o = 1; o < 64; o <<= 1) s += __shfl_xor(s, o);
    float ls = m + __logf(s);
    float* op = out + (size_t)n * D_OUT;
    op[lane]      = l0 - ls;
    op[lane + 64] = l1 - ls;
    if (has2) op[lane + 128] = l2 - ls;
}

// ---------------------------------------------------------------------------
extern "C" void kernel_launch(void* const* d_in, const int* in_sizes, int n_in,
                              void* d_out, int out_size, void* d_ws, size_t ws_size,
                              hipStream_t stream) {
    const float* x     = (const float*)d_in[0];
    const int*   edges = (const int*)d_in[1];   // [2, N_EDGES]
    const float* W1    = (const float*)d_in[2];
    const float* b1    = (const float*)d_in[3];
    const float* W2    = (const float*)d_in[4];
    const float* b2    = (const float*)d_in[5];
    float*       out   = (float*)d_out;

    const int* src = edges;
    const int* dst = edges + N_EDGES;

    int*   ws     = (int*)d_ws;
    int*   deg    = ws + O_DEG;
    int*   rowptr = ws + O_ROW;
    int*   bsum   = ws + O_BSUM;
    float* dinv   = (float*)(ws + O_DINV);
    int*   pos    = ws + O_POS;     // dead after k_fill
    float* bufA   = (float*)(ws + O_BUFA);  // aliases pos
    float* bufB   = (float*)(ws + O_BUFB);  // aliases pos
    int*   col    = ws + O_COL;

    const int B = 256;
    // --- CSR build (6.4M int atomics total) ---
    k_init_deg  <<<N_PAD / B, B, 0, stream>>>(deg);
    k_hist      <<<N_EDGES / B, B, 0, stream>>>(dst, deg, pos);
    k_bsum      <<<N_PAD / B, B, 0, stream>>>(deg, bsum);
    k_scan_bsum <<<1, B, 0, stream>>>(bsum);
    k_scan_final<<<N_PAD / B, B, 0, stream>>>(deg, bsum, rowptr);
    k_dinv      <<<N_PAD / B, B, 0, stream>>>(deg, dinv);
    k_fill      <<<N_EDGES / B, B, 0, stream>>>(src, dst, pos, rowptr, col);

    // --- layer 1: project 128->16, then pull-aggregate ---
    k_lin1  <<<N_NODES / 64, B, 0, stream>>>(x, W1, bufA);
    k_gather<<<N_NODES / 16, B, 0, stream>>>(rowptr, col, dinv, bufA, bufB);
    k_relu  <<<(N_NODES * 4) / B, B, 0, stream>>>((float4*)bufB, b1);

    // --- layer 2 (reassociated): aggregate h in 16-dim, then 16->172 + lsm ---
    k_gather<<<N_NODES / 16, B, 0, stream>>>(rowptr, col, dinv, bufB, bufA);
    k_out   <<<N_NODES / 4, B, 0, stream>>>(bufA, W2, b2, out);
}